// Round 11
// baseline (253.074 us; speedup 1.0000x reference)
//
#include <hip/hip_runtime.h>
#include <math.h>

#define E_ 8
#define T_ 4096
#define K_ 2048
#define I_ 768
#define TWOI 1536
#define NPAIR (2*T_)

typedef unsigned short u16;
typedef signed char i8;
typedef __attribute__((ext_vector_type(8))) __bf16 bf16x8;
typedef __attribute__((ext_vector_type(4))) float f32x4;
typedef __attribute__((ext_vector_type(4))) int i32x4;
typedef __attribute__((ext_vector_type(4))) unsigned u32x4;
typedef __attribute__((ext_vector_type(8))) u16 u16x8;
typedef __attribute__((ext_vector_type(4))) int int4v;
typedef __attribute__((ext_vector_type(4))) float float4v;

typedef __attribute__((address_space(3))) char lds_c;
typedef __attribute__((address_space(1))) const char g_c;

__device__ inline void gld16(const void* g, void* l) {
    __builtin_amdgcn_global_load_lds((g_c*)g, (lds_c*)l, 16, 0, 0);
}

__device__ inline u16 f2bf(float x) {
    unsigned u = __builtin_bit_cast(unsigned, x);
    unsigned r = 0x7fffu + ((u >> 16) & 1u);
    u += r;
    return (u16)(u >> 16);
}
__device__ inline float bf2f(u16 b) {
    unsigned u = ((unsigned)b) << 16;
    return __builtin_bit_cast(float, u);
}

// ternary-code (i8 in {-1,0,1}) -> bf16 {0xBF80,0,0x3F80}, 2 codes per dword
__device__ inline unsigned dq2(unsigned u) {   // u: 2x16 lanes holding code bytes
    unsigned t = u & 0x00010001u;
    unsigned f = (t << 14) - (t << 7);         // 0 or 0x3F80 per lane (no borrow cross)
    unsigned sg = (u & 0x00800080u) << 8;      // sign bit for 0xFF codes
    return f | sg;
}
__device__ inline bf16x8 dq8(unsigned long long v) {
    unsigned d0 = (unsigned)v, d1 = (unsigned)(v >> 32);
    u32x4 w;
    w[0] = dq2((d0 & 0xFFu) | ((d0 & 0xFF00u) << 8));
    w[1] = dq2(((d0 >> 16) & 0xFFu) | ((d0 >> 8) & 0xFF0000u));
    w[2] = dq2((d1 & 0xFFu) | ((d1 & 0xFF00u) << 8));
    w[3] = dq2(((d1 >> 16) & 0xFFu) | ((d1 >> 8) & 0xFF0000u));
    return __builtin_bit_cast(bf16x8, w);
}

// ---------------- routing ----------------
__global__ void k_zero(int* __restrict__ p, int n) {
    int i = blockIdx.x * 256 + threadIdx.x;
    if (i < n) p[i] = 0;
}

__global__ void k_route(const float* __restrict__ logits, int* __restrict__ tid2,
                        float* __restrict__ tw, int* __restrict__ counts) {
    int t = blockIdx.x * 256 + threadIdx.x;
    if (t >= T_) return;
    float l[E_];
#pragma unroll
    for (int e = 0; e < E_; ++e) l[e] = logits[t * E_ + e];
    int i0 = 0; float m0 = l[0];
#pragma unroll
    for (int e = 1; e < E_; ++e) if (l[e] > m0) { m0 = l[e]; i0 = e; }
    int i1 = -1; float m1 = -1e30f;
#pragma unroll
    for (int e = 0; e < E_; ++e) if (e != i0 && l[e] > m1) { m1 = l[e]; i1 = e; }
    float w0 = 1.0f / (1.0f + expf(m1 - m0));
    float w1 = 1.0f - w0;
    tid2[t * 2 + 0] = i0; tid2[t * 2 + 1] = i1;
    tw[t * 2 + 0] = w0;  tw[t * 2 + 1] = w1;
    atomicAdd(&counts[i0], 1);
    atomicAdd(&counts[i1], 1);
}

__global__ void k_scan(const int* __restrict__ counts, int* __restrict__ offsets) {
    if (threadIdx.x == 0) {
        int s = 0;
        for (int e = 0; e < E_; ++e) { offsets[e] = s; s += counts[e]; }
        offsets[E_] = s;
    }
}

__global__ void k_lists(const int* __restrict__ tid2, const int* __restrict__ offsets,
                        int* __restrict__ cursors, int* __restrict__ pairTok) {
    int t = blockIdx.x * 256 + threadIdx.x;
    if (t >= T_) return;
#pragma unroll
    for (int s = 0; s < 2; ++s) {
        int e = tid2[t * 2 + s];
        int pos = atomicAdd(&cursors[e], 1);
        pairTok[offsets[e] + pos] = (t << 1) | s;
    }
}

// ---------------- conversions ----------------
// int32 codes -> i8 (code-1) in {-1,0,1}; used for both w13 and w2
__global__ void k_cvt_codes(const int* __restrict__ q, i8* __restrict__ wc) {
    long idx = ((long)blockIdx.x * 256 + threadIdx.x) * 8;
    const int4v* qp = (const int4v*)(q + idx);
    int4v q0 = qp[0], q1 = qp[1];
    unsigned long long pk = 0;
#pragma unroll
    for (int j = 0; j < 4; ++j)
        pk |= ((unsigned long long)(unsigned char)(char)(q0[j] - 1)) << (8 * j);
#pragma unroll
    for (int j = 0; j < 4; ++j)
        pk |= ((unsigned long long)(unsigned char)(char)(q1[j] - 1)) << (8 * (4 + j));
    *(unsigned long long*)(wc + idx) = pk;
}

// per-pair-row quantization of x*alpha13[e] -> i8 + row scale
__global__ __launch_bounds__(256) void k_qx(
    const float* __restrict__ x, const float* __restrict__ a13,
    const int* __restrict__ pairTok, const int* __restrict__ offsets,
    i8* __restrict__ xq, float* __restrict__ sx)
{
    int p = blockIdx.x;
    int e = 0;
#pragma unroll
    for (int j = 1; j < E_; ++j) if (p >= offsets[j]) e = j;
    int tok = pairTok[p] >> 1;
    int tid = threadIdx.x;
    int i0 = tid * 8;

    float xa[8];
    {
        const float4v* xp = (const float4v*)(x + (long)tok * K_ + i0);
        const float4v* ap = (const float4v*)(a13 + (long)e * K_ + i0);
        float4v x0 = xp[0], x1 = xp[1], a0 = ap[0], a1 = ap[1];
#pragma unroll
        for (int j = 0; j < 4; ++j) { xa[j] = x0[j] * a0[j]; xa[4 + j] = x1[j] * a1[j]; }
    }
    float m = 0.f;
#pragma unroll
    for (int j = 0; j < 8; ++j) m = fmaxf(m, fabsf(xa[j]));
#pragma unroll
    for (int off = 32; off >= 1; off >>= 1) m = fmaxf(m, __shfl_xor(m, off));
    __shared__ float wm[4];
    if ((tid & 63) == 0) wm[tid >> 6] = m;
    __syncthreads();
    m = fmaxf(fmaxf(wm[0], wm[1]), fmaxf(wm[2], wm[3]));
    float inv = (m > 0.f) ? 127.0f / m : 0.f;
    unsigned long long pk = 0;
#pragma unroll
    for (int j = 0; j < 8; ++j) {
        int qv = __float2int_rn(xa[j] * inv);
        pk |= ((unsigned long long)(unsigned char)(char)qv) << (8 * j);
    }
    *(unsigned long long*)(xq + (long)p * K_ + i0) = pk;
    if (tid == 0) sx[p] = m / 127.0f;
}

// ---------------- GEMM1: i8 256x256 2-phase, fused silu*u*alpha2 ----------------
__global__ __launch_bounds__(512, 2) void k_g1i8(
    const i8* __restrict__ A,       // xq [NPAIR][K] list order
    const i8* __restrict__ B,       // wc13 codes [E][2I][K]
    const int* __restrict__ offsets, const float* __restrict__ sx,
    const float* __restrict__ a2,   // alpha2 [E][I]
    u16* __restrict__ C)            // ab [NPAIR][I] = silu(g)*u*alpha2
{
    int bid = blockIdx.x;
    int e  = bid & 7;
    int r_ = bid >> 3;
    int mc = r_ / 6;
    int nch = r_ % 6;
    int base = offsets[e];
    int cnt  = offsets[e + 1] - base;
    int m0 = mc * 256;
    if (m0 >= cnt) return;
    int n0 = nch * 128;

    // single 128 KB block: As = [2][256][128] i8 @0, Bs = [2][256][128] i8 @65536
    __shared__ __attribute__((aligned(16))) i8 SHM[131072];
    i8* As = SHM;
    i8* Bs = SHM + 65536;

    int tid = threadIdx.x;
    int lane = tid & 63;
    int wid = tid >> 6;
    int wr = wid >> 2, wc = wid & 3;
    int l15 = lane & 15;

    const i8* srcA[4];
    const i8* srcB[4];
#pragma unroll
    for (int j = 0; j < 4; ++j) {
        int chunk = j * 512 + tid;          // 0..2047
        int row = chunk >> 3, ch = chunk & 7;
        int colsw = (ch ^ (row & 7)) * 16;
        int ra = m0 + row; if (ra >= cnt) ra = cnt - 1;
        srcA[j] = A + (long)(base + ra) * K_ + colsw;
        int grow = e * TWOI + (row >> 7) * I_ + n0 + (row & 127);
        srcB[j] = B + (long)grow * K_ + colsw;
    }

    auto stage = [&](int bs, int t) {
        int k0 = t * 128;
        i8* dA = As + bs * 32768;
        i8* dB = Bs + bs * 32768;
#pragma unroll
        for (int j = 0; j < 4; ++j) {
            gld16(srcA[j] + k0, dA + j * 8192 + tid * 16);
            gld16(srcB[j] + k0, dB + j * 8192 + tid * 16);
        }
    };

    int kq16 = ((lane >> 4) & 3) * 16;

    i32x4 a[4][2], b[4][2];
    i32x4 acc[8][4];
#pragma unroll
    for (int mf = 0; mf < 8; ++mf)
#pragma unroll
        for (int nf = 0; nf < 4; ++nf)
            acc[mf][nf] = (i32x4){0, 0, 0, 0};

    auto rdA = [&](int bs, int h64) {
#pragma unroll
        for (int mf = 0; mf < 4; ++mf) {
            int row = wr * 128 + h64 + mf * 16 + l15;
            const i8* p = As + bs * 32768 + row * 128;
            int xr = (row & 7) << 4;
            a[mf][0] = *(const i32x4*)(p + ((kq16) ^ xr));
            a[mf][1] = *(const i32x4*)(p + ((64 + kq16) ^ xr));
        }
    };
    auto rdB = [&](int bs) {
#pragma unroll
        for (int nf = 0; nf < 4; ++nf) {
            int row = wc * 64 + nf * 16 + l15;
            const i8* p = Bs + bs * 32768 + row * 128;
            int xr = (row & 7) << 4;
            b[nf][0] = *(const i32x4*)(p + ((kq16) ^ xr));
            b[nf][1] = *(const i32x4*)(p + ((64 + kq16) ^ xr));
        }
    };
    auto mm = [&](int mh) {
#pragma unroll
        for (int ks = 0; ks < 2; ++ks)
#pragma unroll
            for (int mf = 0; mf < 4; ++mf)
#pragma unroll
                for (int nf = 0; nf < 4; ++nf)
                    acc[mh * 4 + mf][nf] = __builtin_amdgcn_mfma_i32_16x16x64_i8(
                        a[mf][ks], b[nf][ks], acc[mh * 4 + mf][nf], 0, 0, 0);
    };
    auto compute = [&](int bs) {
        rdB(bs);
        rdA(bs, 0);
        mm(0);
        rdA(bs, 64);
        mm(1);
    };

    stage(0, 0);
    __syncthreads();
#pragma unroll 1
    for (int t = 0; t < 16; t += 2) {
        stage(1, t + 1);
        compute(0);
        __syncthreads();
        if (t + 2 < 16) stage(0, t + 2);
        compute(1);
        __syncthreads();
    }

    // epilogue: acc -> bf16 in LDS (swizzled, full 128 KB), silu(g)*u*alpha2
    u16* flat = (u16*)SHM;  // 131072 B = [256][256] u16
#pragma unroll
    for (int mf = 0; mf < 8; ++mf)
#pragma unroll
        for (int nf = 0; nf < 4; ++nf)
#pragma unroll
            for (int rg = 0; rg < 4; ++rg) {
                int row = wr * 128 + mf * 16 + (lane >> 4) * 4 + rg;
                int col = wc * 64 + nf * 16 + l15;
                flat[row * 256 + (col ^ ((row & 7) << 3))] = f2bf((float)acc[mf][nf][rg]);
            }
    __syncthreads();
    int row = tid >> 1;
    if (m0 + row < cnt) {
        float s = sx[base + m0 + row];
        int xr = (row & 7) << 3;
        int half = tid & 1;
        u16* dst = C + (long)(base + m0 + row) * I_ + n0 + half * 64;
#pragma unroll
        for (int jj = 0; jj < 8; ++jj) {
            u16x8 gv = *(const u16x8*)&flat[row * 256 + ((half * 64 + jj * 8) ^ xr)];
            u16x8 uv = *(const u16x8*)&flat[row * 256 + ((128 + half * 64 + jj * 8) ^ xr)];
            const float4v* a2p = (const float4v*)(a2 + (long)e * I_ + n0 + half * 64 + jj * 8);
            float4v A0 = a2p[0], A1 = a2p[1];
            u16x8 r;
#pragma unroll
            for (int q = 0; q < 8; ++q) {
                float g = bf2f(gv[q]) * s, u = bf2f(uv[q]) * s;
                float al = (q < 4) ? A0[q] : A1[q - 4];
                r[q] = f2bf(g / (1.0f + expf(-g)) * u * al);
            }
            *(u16x8*)(dst + jj * 8) = r;
        }
    }
}

// ---------------- GEMM2: bf16 A x ternary-code B (in-register dequant) ----------------
// y[m,n] = sum_i ab[m,i] * code2[n,i];  ab already carries alpha2.
__global__ __launch_bounds__(512, 2) void k_g2c(
    const u16* __restrict__ A,      // ab [NPAIR][I] bf16, list order
    const i8* __restrict__ B,       // wc2 codes [E][K][I]
    const int* __restrict__ pairTok, const int* __restrict__ offsets,
    u16* __restrict__ C)            // yb [NPAIR][K] scattered by pair
{
    int bid = blockIdx.x;
    int e  = bid & 7;
    int r_ = bid >> 3;
    int mc = r_ >> 3;               // /8
    int nch = r_ & 7;
    int base = offsets[e];
    int cnt  = offsets[e + 1] - base;
    int m0 = mc * 256;
    if (m0 >= cnt) return;
    int n0 = nch * 256;

    // single 128 KB block: As = [2][256][64] u16 @0 (64 KB),
    // Bs = [2][16384] i8 @65536 (32 KB); epilogue flat uses all 128 KB.
    __shared__ __attribute__((aligned(16))) char SHM[131072];
    u16* As = (u16*)SHM;
    i8*  Bs = (i8*)(SHM + 65536);

    int tid = threadIdx.x;
    int lane = tid & 63;
    int wid = tid >> 6;
    int wr = wid >> 2, wc = wid & 3;
    int l15 = lane & 15;

    // A staging (bf16, 16B=8 elem chunks, swizzle c^(row&7))
    const u16* srcA[2][2];
#pragma unroll
    for (int h = 0; h < 2; ++h)
#pragma unroll
        for (int j = 0; j < 2; ++j) {
            int slot = j * 512 + tid;
            int row = slot >> 3, ch = slot & 7;
            int colsw = (ch ^ (row & 7)) * 8;
            int ra = m0 + h * 128 + row;
            if (ra >= cnt) ra = cnt - 1;
            srcA[h][j] = A + (long)(base + ra) * I_ + colsw;
        }
    // B staging (i8 codes; superrow s holds n-rows {2s,2s+1}, 8x16B chunks, c^(s&7))
    const i8* srcB[2];
#pragma unroll
    for (int j = 0; j < 2; ++j) {
        int slot = j * 512 + tid;       // 0..1023
        int s = slot >> 3, c = slot & 7;
        int cg = c ^ (s & 7);
        int nrow = 2 * s + (cg >> 2);
        int kq = cg & 3;
        srcB[j] = B + (long)(e * K_ + n0 + nrow) * I_ + kq * 16;
    }
    int d0 = tid * 8, d1 = (512 + tid) * 8;

    auto stage = [&](int bs, int t) {
        int k0 = t * 64;
        u16* dA = As + bs * 16384;
        i8* dB = Bs + bs * 16384;
#pragma unroll
        for (int h = 0; h < 2; ++h) {
            gld16(srcA[h][0] + k0, dA + h * 8192 + d0);
            gld16(srcA[h][1] + k0, dA + h * 8192 + d1);
        }
        gld16(srcB[0] + k0, dB + tid * 16);
        gld16(srcB[1] + k0, dB + (512 + tid) * 16);
    };

    int kc0 = ((((lane >> 4) & 3) * 8)) ^ ((lane & 7) * 8);
    int kc1 = (32 + (((lane >> 4) & 3) * 8)) ^ ((lane & 7) * 8);
    int g4 = (lane >> 4) & 3;

    bf16x8 a[4][2], b[4][2];
    f32x4 acc[8][4];
#pragma unroll
    for (int mf = 0; mf < 8; ++mf)
#pragma unroll
        for (int nf = 0; nf < 4; ++nf)
            acc[mf][nf] = (f32x4){0.f, 0.f, 0.f, 0.f};

    auto rdA = [&](int bs, int h64) {
#pragma unroll
        for (int mf = 0; mf < 4; ++mf) {
            const u16* p = As + bs * 16384 + (wr * 128 + h64 + mf * 16 + l15) * 64;
            a[mf][0] = __builtin_bit_cast(bf16x8, *(const u16x8*)(p + kc0));
            a[mf][1] = __builtin_bit_cast(bf16x8, *(const u16x8*)(p + kc1));
        }
    };
    auto rdB = [&](int bs) {
#pragma unroll
        for (int nf = 0; nf < 4; ++nf) {
            int n = wc * 64 + nf * 16 + l15;
            int s = n >> 1, p = n & 1;
#pragma unroll
            for (int ks = 0; ks < 2; ++ks) {
                int cg = p * 4 + ks * 2 + (g4 >> 1);
                int c = cg ^ (s & 7);
                unsigned long long v = *(const unsigned long long*)
                    (Bs + bs * 16384 + s * 128 + c * 16 + (g4 & 1) * 8);
                b[nf][ks] = dq8(v);
            }
        }
    };
    auto mm = [&](int mh) {
#pragma unroll
        for (int ks = 0; ks < 2; ++ks)
#pragma unroll
            for (int mf = 0; mf < 4; ++mf)
#pragma unroll
                for (int nf = 0; nf < 4; ++nf)
                    acc[mh * 4 + mf][nf] = __builtin_amdgcn_mfma_f32_16x16x32_bf16(
                        a[mf][ks], b[nf][ks], acc[mh * 4 + mf][nf], 0, 0, 0);
    };
    auto compute = [&](int bs) {
        rdB(bs);
        rdA(bs, 0);
        mm(0);
        rdA(bs, 64);
        mm(1);
    };

    // NT = 12 (K-dim = I_ = 768, BK = 64)
    stage(0, 0);
    __syncthreads();
#pragma unroll 1
    for (int t = 0; t < 12; t += 2) {
        stage(1, t + 1);
        compute(0);
        __syncthreads();
        if (t + 2 < 12) stage(0, t + 2);
        compute(1);
        __syncthreads();
    }

    // epilogue: repack via swizzled LDS (full 128 KB), scatter rows by pairTok
    u16* flat = (u16*)SHM;  // 131072 B = [256][256] u16
#pragma unroll
    for (int mf = 0; mf < 8; ++mf)
#pragma unroll
        for (int nf = 0; nf < 4; ++nf)
#pragma unroll
            for (int rg = 0; rg < 4; ++rg) {
                int row = wr * 128 + mf * 16 + (lane >> 4) * 4 + rg;
                int col = wc * 64 + nf * 16 + l15;
                flat[row * 256 + (col ^ ((row & 7) << 3))] = f2bf(acc[mf][nf][rg]);
            }
    __syncthreads();
    int row = tid >> 1;
    if (m0 + row < cnt) {
        int xr = (row & 7) << 3;
        int half = tid & 1;
        int pt = pairTok[base + m0 + row];
        u16* dst = C + (long)pt * K_ + n0 + half * 128;
#pragma unroll
        for (int jj = 0; jj < 16; ++jj) {
            *(u16x8*)(dst + jj * 8) =
                *(const u16x8*)&flat[row * 256 + ((half * 128 + jj * 8) ^ xr)];
        }
    }
}

// ---------------- combine ----------------
__global__ void k_combine(const u16* __restrict__ yb, const float* __restrict__ tw,
                          float* __restrict__ out) {
    long idx = ((long)blockIdx.x * 256 + threadIdx.x) * 8;
    int t = (int)(idx >> 11);
    float w0 = tw[t * 2 + 0];
    float w1 = tw[t * 2 + 1];
    u16x8 y0 = *(const u16x8*)(yb + (long)(2 * t) * K_ + (idx & (K_ - 1)));
    u16x8 y1 = *(const u16x8*)(yb + (long)(2 * t + 1) * K_ + (idx & (K_ - 1)));
    float4v o0, o1;
#pragma unroll
    for (int j = 0; j < 4; ++j) o0[j] = w0 * bf2f(y0[j]) + w1 * bf2f(y1[j]);
#pragma unroll
    for (int j = 0; j < 4; ++j) o1[j] = w0 * bf2f(y0[4 + j]) + w1 * bf2f(y1[4 + j]);
    *(float4v*)(out + idx) = o0;
    *(float4v*)(out + idx + 4) = o1;
}

// ---------------- launch ----------------
extern "C" void kernel_launch(void* const* d_in, const int* in_sizes, int n_in,
                              void* d_out, int out_size, void* d_ws, size_t ws_size,
                              hipStream_t stream) {
    const float* x       = (const float*)d_in[0];
    const float* logits  = (const float*)d_in[1];
    const int*   w13q    = (const int*)d_in[2];
    const int*   w2q     = (const int*)d_in[3];
    const float* alpha13 = (const float*)d_in[4];
    const float* alpha2  = (const float*)d_in[5];
    float* out = (float*)d_out;

    char* ws = (char*)d_ws;
    i8*  wc13 = (i8*)(ws);                          // 25165824 B (codes i8)
    i8*  wc2  = (i8*)(ws + 50331648);               // 12582912 B (codes i8)
    i8*  xq   = (i8*)(ws + 75497472);               // 16777216 B
    u16* ab   = (u16*)(ws + 92274688);              // 12582912 B (a*alpha2 bf16)
    u16* yb   = (u16*)(ws + 104857600);             // 33554432 B
    int* pairTok = (int*)(ws + 138412032);          // 8192 ints
    int* tid2    = pairTok + NPAIR;                 // 8192 ints
    float* tw    = (float*)(tid2 + NPAIR);          // 8192 floats
    int* counts  = (int*)(tw + NPAIR);              // 8
    int* offsets = counts + 8;                      // 9
    int* cursors = offsets + 9;                     // 8
    float* sx    = (float*)(cursors + 8);           // 8192 floats

    // routing
    k_zero<<<1, 64, 0, stream>>>(counts, 25);
    k_route<<<T_ / 256, 256, 0, stream>>>(logits, tid2, tw, counts);
    k_scan<<<1, 64, 0, stream>>>(counts, offsets);
    k_lists<<<T_ / 256, 256, 0, stream>>>(tid2, offsets, cursors, pairTok);

    // weight conversions (both to pure ternary codes)
    k_cvt_codes<<<(8L * TWOI * K_) / 8 / 256, 256, 0, stream>>>(w13q, wc13);
    k_cvt_codes<<<(8L * K_ * I_) / 8 / 256, 256, 0, stream>>>(w2q, wc2);

    // per-pair-row i8 quantization of x*alpha13
    k_qx<<<NPAIR, 256, 0, stream>>>(x, alpha13, pairTok, offsets, xq, sx);

    // GEMM1 i8 (M x [128g|128u] x 2048) + fused silu*u*alpha2 -> ab
    k_g1i8<<<8 * (T_ / 256) * 6, 512, 0, stream>>>(xq, wc13, offsets, sx, alpha2, ab);

    // GEMM2 bf16 x code (M x 2048 x 768) -> yb scattered by pair
    k_g2c<<<8 * (T_ / 256) * 8, 512, 0, stream>>>(ab, wc2, pairTok, offsets, yb);

    // combine
    k_combine<<<((long)T_ * K_) / 8 / 256, 256, 0, stream>>>(yb, tw, out);
}

// Round 12
// 208.943 us; speedup vs baseline: 1.2112x; 1.2112x over previous
//
#include <hip/hip_runtime.h>
#include <math.h>

#define E_ 8
#define T_ 4096
#define K_ 2048
#define I_ 768
#define TWOI 1536
#define NPAIR (2*T_)

typedef unsigned short u16;
typedef signed char i8;
typedef __attribute__((ext_vector_type(8))) __bf16 bf16x8;
typedef __attribute__((ext_vector_type(4))) float f32x4;
typedef __attribute__((ext_vector_type(4))) int i32x4;
typedef __attribute__((ext_vector_type(8))) u16 u16x8;
typedef __attribute__((ext_vector_type(4))) int int4v;
typedef __attribute__((ext_vector_type(4))) float float4v;

typedef __attribute__((address_space(3))) char lds_c;
typedef __attribute__((address_space(1))) const char g_c;

__device__ inline void gld16(const void* g, void* l) {
    __builtin_amdgcn_global_load_lds((g_c*)g, (lds_c*)l, 16, 0, 0);
}

__device__ inline u16 f2bf(float x) {
    unsigned u = __builtin_bit_cast(unsigned, x);
    unsigned r = 0x7fffu + ((u >> 16) & 1u);
    u += r;
    return (u16)(u >> 16);
}
__device__ inline float bf2f(u16 b) {
    unsigned u = ((unsigned)b) << 16;
    return __builtin_bit_cast(float, u);
}

// ---------------- fused: route + cvt_w13(codes i8) + cvt_w2(bf16*alpha2) ----------------
#define CVT13_B 12288   // (8*1536*2048)/8/256
#define CVT2_B  6144    // (8*2048*768)/8/256
__global__ __launch_bounds__(256) void k_fusedA(
    const int* __restrict__ w13q, const int* __restrict__ w2q,
    const float* __restrict__ alpha2, const float* __restrict__ logits,
    i8* __restrict__ wc13, u16* __restrict__ wb2,
    int* __restrict__ tid2, float* __restrict__ tw)
{
    int bid = blockIdx.x;
    if (bid < CVT13_B) {
        long idx = ((long)bid * 256 + threadIdx.x) * 8;
        const int4v* qp = (const int4v*)(w13q + idx);
        int4v q0 = qp[0], q1 = qp[1];
        unsigned long long pk = 0;
#pragma unroll
        for (int j = 0; j < 4; ++j)
            pk |= ((unsigned long long)(unsigned char)(char)(q0[j] - 1)) << (8 * j);
#pragma unroll
        for (int j = 0; j < 4; ++j)
            pk |= ((unsigned long long)(unsigned char)(char)(q1[j] - 1)) << (8 * (4 + j));
        *(unsigned long long*)(wc13 + idx) = pk;
    } else if (bid < CVT13_B + CVT2_B) {
        long idx = ((long)(bid - CVT13_B) * 256 + threadIdx.x) * 8;
        int i = (int)(idx % I_);
        int e = (int)(idx / ((long)K_ * I_));
        const int4v* qp = (const int4v*)(w2q + idx);
        int4v q0 = qp[0], q1 = qp[1];
        const float4v* ap = (const float4v*)(alpha2 + e * I_ + i);
        float4v a0 = ap[0], a1 = ap[1];
        u16x8 r;
        r[0] = f2bf((float)(q0[0] - 1) * a0[0]);
        r[1] = f2bf((float)(q0[1] - 1) * a0[1]);
        r[2] = f2bf((float)(q0[2] - 1) * a0[2]);
        r[3] = f2bf((float)(q0[3] - 1) * a0[3]);
        r[4] = f2bf((float)(q1[0] - 1) * a1[0]);
        r[5] = f2bf((float)(q1[1] - 1) * a1[1]);
        r[6] = f2bf((float)(q1[2] - 1) * a1[2]);
        r[7] = f2bf((float)(q1[3] - 1) * a1[3]);
        *(u16x8*)(wb2 + idx) = r;
    } else {
        int t = (bid - CVT13_B - CVT2_B) * 256 + threadIdx.x;
        float l[E_];
#pragma unroll
        for (int e = 0; e < E_; ++e) l[e] = logits[t * E_ + e];
        int i0 = 0; float m0 = l[0];
#pragma unroll
        for (int e = 1; e < E_; ++e) if (l[e] > m0) { m0 = l[e]; i0 = e; }
        int i1 = -1; float m1 = -1e30f;
#pragma unroll
        for (int e = 0; e < E_; ++e) if (e != i0 && l[e] > m1) { m1 = l[e]; i1 = e; }
        float w0 = 1.0f / (1.0f + expf(m1 - m0));
        tid2[t * 2 + 0] = i0; tid2[t * 2 + 1] = i1;
        tw[t * 2 + 0] = w0;  tw[t * 2 + 1] = 1.0f - w0;
    }
}

// ---------------- scan+hist: counts from tid2 (no pre-zero), offsets, cursors=0 ----------------
__global__ __launch_bounds__(1024) void k_scanhist(
    const int* __restrict__ tid2, int* __restrict__ offsets, int* __restrict__ cursors)
{
    int tid = threadIdx.x;
    int c[E_];
#pragma unroll
    for (int e = 0; e < E_; ++e) c[e] = 0;
#pragma unroll
    for (int j = 0; j < 8; ++j) {
        int v = tid2[tid * 8 + j];
#pragma unroll
        for (int e = 0; e < E_; ++e) c[e] += (v == e) ? 1 : 0;
    }
#pragma unroll
    for (int e = 0; e < E_; ++e)
#pragma unroll
        for (int off = 32; off >= 1; off >>= 1)
            c[e] += __shfl_xor(c[e], off);
    __shared__ int wsum[16][E_];
    if ((tid & 63) == 0)
#pragma unroll
        for (int e = 0; e < E_; ++e) wsum[tid >> 6][e] = c[e];
    __syncthreads();
    if (tid == 0) {
        int s = 0;
        for (int e = 0; e < E_; ++e) {
            int ce = 0;
            for (int w = 0; w < 16; ++w) ce += wsum[w][e];
            offsets[e] = s; s += ce;
        }
        offsets[E_] = s;
    }
    if (tid < E_) cursors[tid] = 0;
}

__global__ void k_lists(const int* __restrict__ tid2, const int* __restrict__ offsets,
                        int* __restrict__ cursors, int* __restrict__ pairTok) {
    int t = blockIdx.x * 256 + threadIdx.x;
    if (t >= T_) return;
#pragma unroll
    for (int s = 0; s < 2; ++s) {
        int e = tid2[t * 2 + s];
        int pos = atomicAdd(&cursors[e], 1);
        pairTok[offsets[e] + pos] = (t << 1) | s;
    }
}

// per-pair-row quantization of x*alpha13[e] -> i8 + row scale
__global__ __launch_bounds__(256) void k_qx(
    const float* __restrict__ x, const float* __restrict__ a13,
    const int* __restrict__ pairTok, const int* __restrict__ offsets,
    i8* __restrict__ xq, float* __restrict__ sx)
{
    int p = blockIdx.x;
    int e = 0;
#pragma unroll
    for (int j = 1; j < E_; ++j) if (p >= offsets[j]) e = j;
    int tok = pairTok[p] >> 1;
    int tid = threadIdx.x;
    int i0 = tid * 8;

    float xa[8];
    {
        const float4v* xp = (const float4v*)(x + (long)tok * K_ + i0);
        const float4v* ap = (const float4v*)(a13 + (long)e * K_ + i0);
        float4v x0 = xp[0], x1 = xp[1], a0 = ap[0], a1 = ap[1];
#pragma unroll
        for (int j = 0; j < 4; ++j) { xa[j] = x0[j] * a0[j]; xa[4 + j] = x1[j] * a1[j]; }
    }
    float m = 0.f;
#pragma unroll
    for (int j = 0; j < 8; ++j) m = fmaxf(m, fabsf(xa[j]));
#pragma unroll
    for (int off = 32; off >= 1; off >>= 1) m = fmaxf(m, __shfl_xor(m, off));
    __shared__ float wm[4];
    if ((tid & 63) == 0) wm[tid >> 6] = m;
    __syncthreads();
    m = fmaxf(fmaxf(wm[0], wm[1]), fmaxf(wm[2], wm[3]));
    float inv = (m > 0.f) ? 127.0f / m : 0.f;
    unsigned long long pk = 0;
#pragma unroll
    for (int j = 0; j < 8; ++j) {
        int qv = __float2int_rn(xa[j] * inv);
        pk |= ((unsigned long long)(unsigned char)(char)qv) << (8 * j);
    }
    *(unsigned long long*)(xq + (long)p * K_ + i0) = pk;
    if (tid == 0) sx[p] = m / 127.0f;
}

// ---------------- GEMM1: i8 256x256 2-phase, fused silu*u ----------------
__global__ __launch_bounds__(512, 2) void k_g1i8(
    const i8* __restrict__ A,       // xq [NPAIR][K] list order
    const i8* __restrict__ B,       // wc13 codes [E][2I][K]
    const int* __restrict__ offsets, const float* __restrict__ sx,
    u16* __restrict__ C)            // ab [NPAIR][I] = silu(g)*u
{
    int bid = blockIdx.x;
    int e  = bid & 7;
    int r_ = bid >> 3;
    int mc = r_ / 6;
    int nch = r_ % 6;
    int base = offsets[e];
    int cnt  = offsets[e + 1] - base;
    int m0 = mc * 256;
    if (m0 >= cnt) return;
    int n0 = nch * 128;

    __shared__ __attribute__((aligned(16))) i8 SHM[131072];
    i8* As = SHM;
    i8* Bs = SHM + 65536;

    int tid = threadIdx.x;
    int lane = tid & 63;
    int wid = tid >> 6;
    int wr = wid >> 2, wc = wid & 3;
    int l15 = lane & 15;

    const i8* srcA[4];
    const i8* srcB[4];
#pragma unroll
    for (int j = 0; j < 4; ++j) {
        int chunk = j * 512 + tid;
        int row = chunk >> 3, ch = chunk & 7;
        int colsw = (ch ^ (row & 7)) * 16;
        int ra = m0 + row; if (ra >= cnt) ra = cnt - 1;
        srcA[j] = A + (long)(base + ra) * K_ + colsw;
        int grow = e * TWOI + (row >> 7) * I_ + n0 + (row & 127);
        srcB[j] = B + (long)grow * K_ + colsw;
    }

    auto stage = [&](int bs, int t) {
        int k0 = t * 128;
        i8* dA = As + bs * 32768;
        i8* dB = Bs + bs * 32768;
#pragma unroll
        for (int j = 0; j < 4; ++j) {
            gld16(srcA[j] + k0, dA + j * 8192 + tid * 16);
            gld16(srcB[j] + k0, dB + j * 8192 + tid * 16);
        }
    };

    int kq16 = ((lane >> 4) & 3) * 16;

    i32x4 a[4][2], b[4][2];
    i32x4 acc[8][4];
#pragma unroll
    for (int mf = 0; mf < 8; ++mf)
#pragma unroll
        for (int nf = 0; nf < 4; ++nf)
            acc[mf][nf] = (i32x4){0, 0, 0, 0};

    auto rdA = [&](int bs, int h64) {
#pragma unroll
        for (int mf = 0; mf < 4; ++mf) {
            int row = wr * 128 + h64 + mf * 16 + l15;
            const i8* p = As + bs * 32768 + row * 128;
            int xr = (row & 7) << 4;
            a[mf][0] = *(const i32x4*)(p + ((kq16) ^ xr));
            a[mf][1] = *(const i32x4*)(p + ((64 + kq16) ^ xr));
        }
    };
    auto rdB = [&](int bs) {
#pragma unroll
        for (int nf = 0; nf < 4; ++nf) {
            int row = wc * 64 + nf * 16 + l15;
            const i8* p = Bs + bs * 32768 + row * 128;
            int xr = (row & 7) << 4;
            b[nf][0] = *(const i32x4*)(p + ((kq16) ^ xr));
            b[nf][1] = *(const i32x4*)(p + ((64 + kq16) ^ xr));
        }
    };
    auto mm = [&](int mh) {
#pragma unroll
        for (int ks = 0; ks < 2; ++ks)
#pragma unroll
            for (int mf = 0; mf < 4; ++mf)
#pragma unroll
                for (int nf = 0; nf < 4; ++nf)
                    acc[mh * 4 + mf][nf] = __builtin_amdgcn_mfma_i32_16x16x64_i8(
                        a[mf][ks], b[nf][ks], acc[mh * 4 + mf][nf], 0, 0, 0);
    };
    auto compute = [&](int bs) {
        rdB(bs);
        rdA(bs, 0);
        mm(0);
        rdA(bs, 64);
        mm(1);
    };

    stage(0, 0);
    __syncthreads();
#pragma unroll 1
    for (int t = 0; t < 16; t += 2) {
        stage(1, t + 1);
        compute(0);
        __syncthreads();
        if (t + 2 < 16) stage(0, t + 2);
        compute(1);
        __syncthreads();
    }

    u16* flat = (u16*)SHM;  // 131072 B = [256][256] u16
#pragma unroll
    for (int mf = 0; mf < 8; ++mf)
#pragma unroll
        for (int nf = 0; nf < 4; ++nf)
#pragma unroll
            for (int rg = 0; rg < 4; ++rg) {
                int row = wr * 128 + mf * 16 + (lane >> 4) * 4 + rg;
                int col = wc * 64 + nf * 16 + l15;
                flat[row * 256 + (col ^ ((row & 7) << 3))] = f2bf((float)acc[mf][nf][rg]);
            }
    __syncthreads();
    int row = tid >> 1;
    if (m0 + row < cnt) {
        float s = sx[base + m0 + row];
        int xr = (row & 7) << 3;
        int half = tid & 1;
        u16* dst = C + (long)(base + m0 + row) * I_ + n0 + half * 64;
#pragma unroll
        for (int jj = 0; jj < 8; ++jj) {
            u16x8 gv = *(const u16x8*)&flat[row * 256 + ((half * 64 + jj * 8) ^ xr)];
            u16x8 uv = *(const u16x8*)&flat[row * 256 + ((128 + half * 64 + jj * 8) ^ xr)];
            u16x8 r;
#pragma unroll
            for (int q = 0; q < 8; ++q) {
                float g = bf2f(gv[q]) * s, u = bf2f(uv[q]) * s;
                r[q] = f2bf(g / (1.0f + expf(-g)) * u);
            }
            *(u16x8*)(dst + jj * 8) = r;
        }
    }
}

// ---------------- GEMM2: bf16 256x256 2-phase (R9 structure, explicit SHM) ----------------
__global__ __launch_bounds__(512, 2) void k_g2(
    const u16* __restrict__ A,      // ab [NPAIR][I] bf16, list order
    const u16* __restrict__ B,      // wb2 [E][K][I] bf16 (alpha2 folded)
    const int* __restrict__ pairTok, const int* __restrict__ offsets,
    u16* __restrict__ C)            // yb [NPAIR][K] scattered by pair
{
    int bid = blockIdx.x;
    int e  = bid & 7;
    int r_ = bid >> 3;
    int mc = r_ >> 3;
    int nch = r_ & 7;
    int base = offsets[e];
    int cnt  = offsets[e + 1] - base;
    int m0 = mc * 256;
    if (m0 >= cnt) return;
    int n0 = nch * 256;

    __shared__ __attribute__((aligned(16))) char SHM[131072];
    u16* ldsA = (u16*)SHM;               // [2][256][64] u16 = 64 KB
    u16* ldsB = (u16*)(SHM + 65536);     // [2][256][64] u16 = 64 KB

    int tid = threadIdx.x;
    int lane = tid & 63;
    int wid = tid >> 6;
    int wr = wid >> 2, wc = wid & 3;
    int l15 = lane & 15;

    const u16* srcA[2][2];
    const u16* srcB[2][2];
#pragma unroll
    for (int h = 0; h < 2; ++h)
#pragma unroll
        for (int j = 0; j < 2; ++j) {
            int slot = j * 512 + tid;
            int row = slot >> 3, ch = slot & 7;
            int colsw = (ch ^ (row & 7)) * 8;
            int ra = m0 + h * 128 + row;
            if (ra >= cnt) ra = cnt - 1;
            srcA[h][j] = A + (long)(base + ra) * I_ + colsw;
            long brow = (long)e * K_ + n0 + h * 128 + row;
            srcB[h][j] = B + brow * (long)I_ + colsw;
        }
    int d0 = tid * 8, d1 = (512 + tid) * 8;

    auto stage = [&](int bs, int t) {
        int k0 = t * 64;
        u16* dA = ldsA + bs * 16384;
        u16* dB = ldsB + bs * 16384;
#pragma unroll
        for (int h = 0; h < 2; ++h) {
            gld16(srcA[h][0] + k0, dA + h * 8192 + d0);
            gld16(srcA[h][1] + k0, dA + h * 8192 + d1);
            gld16(srcB[h][0] + k0, dB + h * 8192 + d0);
            gld16(srcB[h][1] + k0, dB + h * 8192 + d1);
        }
    };

    int kc0 = ((((lane >> 4) & 3) * 8)) ^ ((lane & 7) * 8);
    int kc1 = (32 + (((lane >> 4) & 3) * 8)) ^ ((lane & 7) * 8);

    bf16x8 a[4][2], b[4][2];
    f32x4 acc[8][4];
#pragma unroll
    for (int mf = 0; mf < 8; ++mf)
#pragma unroll
        for (int nf = 0; nf < 4; ++nf)
            acc[mf][nf] = (f32x4){0.f, 0.f, 0.f, 0.f};

    auto rdA = [&](int bs, int h64) {
#pragma unroll
        for (int mf = 0; mf < 4; ++mf) {
            const u16* p = ldsA + bs * 16384 + (wr * 128 + h64 + mf * 16 + l15) * 64;
            a[mf][0] = __builtin_bit_cast(bf16x8, *(const u16x8*)(p + kc0));
            a[mf][1] = __builtin_bit_cast(bf16x8, *(const u16x8*)(p + kc1));
        }
    };
    auto rdB = [&](int bs) {
#pragma unroll
        for (int nf = 0; nf < 4; ++nf) {
            const u16* p = ldsB + bs * 16384 + (wc * 64 + nf * 16 + l15) * 64;
            b[nf][0] = __builtin_bit_cast(bf16x8, *(const u16x8*)(p + kc0));
            b[nf][1] = __builtin_bit_cast(bf16x8, *(const u16x8*)(p + kc1));
        }
    };
    auto mm = [&](int mh) {
#pragma unroll
        for (int ks = 0; ks < 2; ++ks)
#pragma unroll
            for (int mf = 0; mf < 4; ++mf)
#pragma unroll
                for (int nf = 0; nf < 4; ++nf)
                    acc[mh * 4 + mf][nf] = __builtin_amdgcn_mfma_f32_16x16x32_bf16(
                        a[mf][ks], b[nf][ks], acc[mh * 4 + mf][nf], 0, 0, 0);
    };
    auto compute = [&](int bs) {
        rdB(bs);
        rdA(bs, 0);
        mm(0);
        rdA(bs, 64);
        mm(1);
    };

    // NT = 12 (K-dim = I_ = 768, BK = 64)
    stage(0, 0);
    __syncthreads();
#pragma unroll 1
    for (int t = 0; t < 12; t += 2) {
        stage(1, t + 1);
        compute(0);
        __syncthreads();
        if (t + 2 < 12) stage(0, t + 2);
        compute(1);
        __syncthreads();
    }

    u16* flat = (u16*)SHM;  // 131072 B = [256][256] u16
#pragma unroll
    for (int mf = 0; mf < 8; ++mf)
#pragma unroll
        for (int nf = 0; nf < 4; ++nf)
#pragma unroll
            for (int rg = 0; rg < 4; ++rg) {
                int row = wr * 128 + mf * 16 + (lane >> 4) * 4 + rg;
                int col = wc * 64 + nf * 16 + l15;
                flat[row * 256 + (col ^ ((row & 7) << 3))] = f2bf(acc[mf][nf][rg]);
            }
    __syncthreads();
    int row = tid >> 1;
    if (m0 + row < cnt) {
        int xr = (row & 7) << 3;
        int half = tid & 1;
        int pt = pairTok[base + m0 + row];
        u16* dst = C + (long)pt * K_ + n0 + half * 128;
#pragma unroll
        for (int jj = 0; jj < 16; ++jj) {
            *(u16x8*)(dst + jj * 8) =
                *(const u16x8*)&flat[row * 256 + ((half * 128 + jj * 8) ^ xr)];
        }
    }
}

// ---------------- combine ----------------
__global__ void k_combine(const u16* __restrict__ yb, const float* __restrict__ tw,
                          float* __restrict__ out) {
    long idx = ((long)blockIdx.x * 256 + threadIdx.x) * 8;
    int t = (int)(idx >> 11);
    float w0 = tw[t * 2 + 0];
    float w1 = tw[t * 2 + 1];
    u16x8 y0 = *(const u16x8*)(yb + (long)(2 * t) * K_ + (idx & (K_ - 1)));
    u16x8 y1 = *(const u16x8*)(yb + (long)(2 * t + 1) * K_ + (idx & (K_ - 1)));
    float4v o0, o1;
#pragma unroll
    for (int j = 0; j < 4; ++j) o0[j] = w0 * bf2f(y0[j]) + w1 * bf2f(y1[j]);
#pragma unroll
    for (int j = 0; j < 4; ++j) o1[j] = w0 * bf2f(y0[4 + j]) + w1 * bf2f(y1[4 + j]);
    *(float4v*)(out + idx) = o0;
    *(float4v*)(out + idx + 4) = o1;
}

// ---------------- launch ----------------
extern "C" void kernel_launch(void* const* d_in, const int* in_sizes, int n_in,
                              void* d_out, int out_size, void* d_ws, size_t ws_size,
                              hipStream_t stream) {
    const float* x       = (const float*)d_in[0];
    const float* logits  = (const float*)d_in[1];
    const int*   w13q    = (const int*)d_in[2];
    const int*   w2q     = (const int*)d_in[3];
    const float* alpha13 = (const float*)d_in[4];
    const float* alpha2  = (const float*)d_in[5];
    float* out = (float*)d_out;

    char* ws = (char*)d_ws;
    i8*  wc13 = (i8*)(ws);                          // 25165824 B (codes i8)
    u16* wb2  = (u16*)(ws + 50331648);              // 25165824 B (bf16, alpha2 folded)
    i8*  xq   = (i8*)(ws + 75497472);               // 16777216 B
    u16* ab   = (u16*)(ws + 92274688);              // 12582912 B (silu*u bf16)
    u16* yb   = (u16*)(ws + 104857600);             // 33554432 B
    int* pairTok = (int*)(ws + 138412032);          // 8192 ints
    int* tid2    = pairTok + NPAIR;                 // 8192 ints
    float* tw    = (float*)(tid2 + NPAIR);          // 8192 floats
    int* counts  = (int*)(tw + NPAIR);              // 8 (unused)
    int* offsets = counts + 8;                      // 9
    int* cursors = offsets + 9;                     // 8
    float* sx    = (float*)(cursors + 8);           // 8192 floats

    // fused: routing(top2) + both weight conversions
    k_fusedA<<<CVT13_B + CVT2_B + T_ / 256, 256, 0, stream>>>(
        w13q, w2q, alpha2, logits, wc13, wb2, tid2, tw);

    // histogram + scan + cursor zero (1 block)
    k_scanhist<<<1, 1024, 0, stream>>>(tid2, offsets, cursors);

    // per-expert token lists
    k_lists<<<T_ / 256, 256, 0, stream>>>(tid2, offsets, cursors, pairTok);

    // per-pair-row i8 quantization of x*alpha13
    k_qx<<<NPAIR, 256, 0, stream>>>(x, alpha13, pairTok, offsets, xq, sx);

    // GEMM1 i8 (M x [128g|128u] x 2048) + fused silu*u -> ab
    k_g1i8<<<8 * (T_ / 256) * 6, 512, 0, stream>>>(xq, wc13, offsets, sx, ab);

    // GEMM2 bf16 (M x 2048 x 768) -> yb scattered by pair
    k_g2<<<8 * (T_ / 256) * (K_ / 256), 512, 0, stream>>>(ab, wb2, pairTok, offsets, yb);

    // combine
    k_combine<<<((long)T_ * K_) / 8 / 256, 256, 0, stream>>>(yb, tw, out);
}

// Round 13
// 189.467 us; speedup vs baseline: 1.3357x; 1.1028x over previous
//
#include <hip/hip_runtime.h>
#include <math.h>

#define E_ 8
#define T_ 4096
#define K_ 2048
#define I_ 768
#define TWOI 1536
#define NPAIR (2*T_)

typedef unsigned short u16;
typedef signed char i8;
typedef __attribute__((ext_vector_type(8))) __bf16 bf16x8;
typedef __attribute__((ext_vector_type(4))) float f32x4;
typedef __attribute__((ext_vector_type(4))) int i32x4;
typedef __attribute__((ext_vector_type(4))) unsigned u32x4;
typedef __attribute__((ext_vector_type(8))) u16 u16x8;
typedef __attribute__((ext_vector_type(4))) int int4v;
typedef __attribute__((ext_vector_type(4))) float float4v;

typedef __attribute__((address_space(3))) char lds_c;
typedef __attribute__((address_space(1))) const char g_c;

__device__ inline void gld16(const void* g, void* l) {
    __builtin_amdgcn_global_load_lds((g_c*)g, (lds_c*)l, 16, 0, 0);
}

__device__ inline u16 f2bf(float x) {
    unsigned u = __builtin_bit_cast(unsigned, x);
    unsigned r = 0x7fffu + ((u >> 16) & 1u);
    u += r;
    return (u16)(u >> 16);
}
__device__ inline float bf2f(u16 b) {
    unsigned u = ((unsigned)b) << 16;
    return __builtin_bit_cast(float, u);
}
__device__ inline unsigned pack4(int4v q) {
    return (unsigned)((unsigned char)(char)(q[0] - 1))
         | ((unsigned)((unsigned char)(char)(q[1] - 1)) << 8)
         | ((unsigned)((unsigned char)(char)(q[2] - 1)) << 16)
         | ((unsigned)((unsigned char)(char)(q[3] - 1)) << 24);
}

// ---------------- fused: cvt_w13 + cvt_w2 + route+qx (self-routed) ----------------
#define CVT13_B 6144    // (8*1536*2048)/16/256
#define CVT2_B  3072    // (8*2048*768)/16/256
#define QX_BASE (CVT13_B + CVT2_B)   // 9216; qx blocks = NPAIR = 8192
__global__ __launch_bounds__(256) void k_fusedA(
    const int* __restrict__ w13q, const int* __restrict__ w2q,
    const float* __restrict__ alpha2, const float* __restrict__ logits,
    const float* __restrict__ x, const float* __restrict__ alpha13,
    i8* __restrict__ wc13, u16* __restrict__ wb2,
    i8* __restrict__ xq, float* __restrict__ sx,
    int* __restrict__ tid2, float* __restrict__ tw, int* __restrict__ cursors)
{
    __shared__ float wm[4];
    int bid = blockIdx.x;
    int tid = threadIdx.x;
    if (bid < CVT13_B) {
        long idx = ((long)bid * 256 + tid) * 16;
        const int4v* qp = (const int4v*)(w13q + idx);
        int4v q0 = qp[0], q1 = qp[1], q2 = qp[2], q3 = qp[3];
        u32x4 r;
        r[0] = pack4(q0); r[1] = pack4(q1); r[2] = pack4(q2); r[3] = pack4(q3);
        *(u32x4*)(wc13 + idx) = r;
    } else if (bid < QX_BASE) {
        long idx = ((long)(bid - CVT13_B) * 256 + tid) * 16;
        int i = (int)(idx % I_);
        int e = (int)(idx / ((long)K_ * I_));
        const int4v* qp = (const int4v*)(w2q + idx);
        const float4v* ap = (const float4v*)(alpha2 + e * I_ + i);
        u16x8 r0, r1;
#pragma unroll
        for (int h = 0; h < 2; ++h) {
            int4v qa = qp[2 * h], qb = qp[2 * h + 1];
            float4v a0 = ap[2 * h], a1 = ap[2 * h + 1];
            u16x8 r;
            r[0] = f2bf((float)(qa[0] - 1) * a0[0]);
            r[1] = f2bf((float)(qa[1] - 1) * a0[1]);
            r[2] = f2bf((float)(qa[2] - 1) * a0[2]);
            r[3] = f2bf((float)(qa[3] - 1) * a0[3]);
            r[4] = f2bf((float)(qb[0] - 1) * a1[0]);
            r[5] = f2bf((float)(qb[1] - 1) * a1[1]);
            r[6] = f2bf((float)(qb[2] - 1) * a1[2]);
            r[7] = f2bf((float)(qb[3] - 1) * a1[3]);
            if (h == 0) r0 = r; else r1 = r;
        }
        *(u16x8*)(wb2 + idx) = r0;
        *(u16x8*)(wb2 + idx + 8) = r1;
    } else {
        // route + per-pair-row i8 quantization, no cross-block deps
        int p = bid - QX_BASE;       // 0..NPAIR-1
        int t = p >> 1, s = p & 1;
        float l[E_];
#pragma unroll
        for (int e = 0; e < E_; ++e) l[e] = logits[t * E_ + e];
        int e0 = 0; float mx0 = l[0];
#pragma unroll
        for (int e = 1; e < E_; ++e) if (l[e] > mx0) { mx0 = l[e]; e0 = e; }
        int e1 = -1; float mx1 = -1e30f;
#pragma unroll
        for (int e = 0; e < E_; ++e) if (e != e0 && l[e] > mx1) { mx1 = l[e]; e1 = e; }
        int e = s ? e1 : e0;

        int c0 = tid * 8;
        float xa[8];
        {
            const float4v* xp = (const float4v*)(x + (long)t * K_ + c0);
            const float4v* ap = (const float4v*)(alpha13 + (long)e * K_ + c0);
            float4v x0 = xp[0], x1 = xp[1], a0 = ap[0], a1 = ap[1];
#pragma unroll
            for (int j = 0; j < 4; ++j) { xa[j] = x0[j] * a0[j]; xa[4 + j] = x1[j] * a1[j]; }
        }
        float m = 0.f;
#pragma unroll
        for (int j = 0; j < 8; ++j) m = fmaxf(m, fabsf(xa[j]));
#pragma unroll
        for (int off = 32; off >= 1; off >>= 1) m = fmaxf(m, __shfl_xor(m, off));
        if ((tid & 63) == 0) wm[tid >> 6] = m;
        __syncthreads();
        m = fmaxf(fmaxf(wm[0], wm[1]), fmaxf(wm[2], wm[3]));
        float inv = (m > 0.f) ? 127.0f / m : 0.f;
        unsigned long long pk = 0;
#pragma unroll
        for (int j = 0; j < 8; ++j) {
            int qv = __float2int_rn(xa[j] * inv);
            pk |= ((unsigned long long)(unsigned char)(char)qv) << (8 * j);
        }
        *(unsigned long long*)(xq + (long)p * K_ + c0) = pk;
        if (tid == 0) {
            sx[p] = m / 127.0f;
            if (!s) {
                tid2[2 * t + 0] = e0; tid2[2 * t + 1] = e1;
                float w0 = 1.0f / (1.0f + expf(mx1 - mx0));
                tw[2 * t + 0] = w0; tw[2 * t + 1] = 1.0f - w0;
            }
        }
        if (p == 0 && tid < E_) cursors[tid] = 0;
    }
}

// ---------------- lists2: redundant histogram + offsets + pairTok (one dispatch) ----------------
__global__ __launch_bounds__(256) void k_lists2(
    const int* __restrict__ tid2, int* __restrict__ offsets,
    int* __restrict__ cursors, int* __restrict__ pairTok)
{
    int tid = threadIdx.x;
    int c[E_];
#pragma unroll
    for (int e = 0; e < E_; ++e) c[e] = 0;
    for (int j = 0; j < 32; ++j) {
        int v = tid2[tid * 32 + j];
#pragma unroll
        for (int e = 0; e < E_; ++e) c[e] += (v == e) ? 1 : 0;
    }
#pragma unroll
    for (int e = 0; e < E_; ++e)
#pragma unroll
        for (int off = 32; off >= 1; off >>= 1)
            c[e] += __shfl_xor(c[e], off);
    __shared__ int ws[4][E_];
    __shared__ int offs[E_ + 1];
    if ((tid & 63) == 0)
#pragma unroll
        for (int e = 0; e < E_; ++e) ws[tid >> 6][e] = c[e];
    __syncthreads();
    if (tid == 0) {
        int s2 = 0;
        for (int e = 0; e < E_; ++e) {
            int ce = ws[0][e] + ws[1][e] + ws[2][e] + ws[3][e];
            offs[e] = s2; s2 += ce;
        }
        offs[E_] = s2;
        if (blockIdx.x == 0)
            for (int e = 0; e <= E_; ++e) offsets[e] = offs[e];
    }
    __syncthreads();
    int t = blockIdx.x * 256 + tid;
#pragma unroll
    for (int s = 0; s < 2; ++s) {
        int e = tid2[t * 2 + s];
        int pos = atomicAdd(&cursors[e], 1);
        pairTok[offs[e] + pos] = (t << 1) | s;
    }
}

// ---------------- GEMM1: i8 256x256 2-phase, fused silu*u (xq pair-indexed) ----------------
__global__ __launch_bounds__(512, 2) void k_g1i8(
    const i8* __restrict__ A,       // xq [NPAIR][K] pair-id order
    const i8* __restrict__ B,       // wc13 codes [E][2I][K]
    const int* __restrict__ pairTok, const int* __restrict__ offsets,
    const float* __restrict__ sx,   // [NPAIR] pair-id order
    u16* __restrict__ C)            // ab [NPAIR][I] list order = silu(g)*u
{
    int bid = blockIdx.x;
    int e  = bid & 7;
    int r_ = bid >> 3;
    int mc = r_ / 6;
    int nch = r_ % 6;
    int base = offsets[e];
    int cnt  = offsets[e + 1] - base;
    int m0 = mc * 256;
    if (m0 >= cnt) return;
    int n0 = nch * 128;

    __shared__ __attribute__((aligned(16))) i8 SHM[131072];
    i8* As = SHM;
    i8* Bs = SHM + 65536;

    int tid = threadIdx.x;
    int lane = tid & 63;
    int wid = tid >> 6;
    int wr = wid >> 2, wc = wid & 3;
    int l15 = lane & 15;

    const i8* srcA[4];
    const i8* srcB[4];
#pragma unroll
    for (int j = 0; j < 4; ++j) {
        int chunk = j * 512 + tid;
        int row = chunk >> 3, ch = chunk & 7;
        int colsw = (ch ^ (row & 7)) * 16;
        int ra = m0 + row; if (ra >= cnt) ra = cnt - 1;
        srcA[j] = A + (long)pairTok[base + ra] * K_ + colsw;
        int grow = e * TWOI + (row >> 7) * I_ + n0 + (row & 127);
        srcB[j] = B + (long)grow * K_ + colsw;
    }

    auto stage = [&](int bs, int t) {
        int k0 = t * 128;
        i8* dA = As + bs * 32768;
        i8* dB = Bs + bs * 32768;
#pragma unroll
        for (int j = 0; j < 4; ++j) {
            gld16(srcA[j] + k0, dA + j * 8192 + tid * 16);
            gld16(srcB[j] + k0, dB + j * 8192 + tid * 16);
        }
    };

    int kq16 = ((lane >> 4) & 3) * 16;

    i32x4 a[4][2], b[4][2];
    i32x4 acc[8][4];
#pragma unroll
    for (int mf = 0; mf < 8; ++mf)
#pragma unroll
        for (int nf = 0; nf < 4; ++nf)
            acc[mf][nf] = (i32x4){0, 0, 0, 0};

    auto rdA = [&](int bs, int h64) {
#pragma unroll
        for (int mf = 0; mf < 4; ++mf) {
            int row = wr * 128 + h64 + mf * 16 + l15;
            const i8* p = As + bs * 32768 + row * 128;
            int xr = (row & 7) << 4;
            a[mf][0] = *(const i32x4*)(p + ((kq16) ^ xr));
            a[mf][1] = *(const i32x4*)(p + ((64 + kq16) ^ xr));
        }
    };
    auto rdB = [&](int bs) {
#pragma unroll
        for (int nf = 0; nf < 4; ++nf) {
            int row = wc * 64 + nf * 16 + l15;
            const i8* p = Bs + bs * 32768 + row * 128;
            int xr = (row & 7) << 4;
            b[nf][0] = *(const i32x4*)(p + ((kq16) ^ xr));
            b[nf][1] = *(const i32x4*)(p + ((64 + kq16) ^ xr));
        }
    };
    auto mm = [&](int mh) {
#pragma unroll
        for (int ks = 0; ks < 2; ++ks)
#pragma unroll
            for (int mf = 0; mf < 4; ++mf)
#pragma unroll
                for (int nf = 0; nf < 4; ++nf)
                    acc[mh * 4 + mf][nf] = __builtin_amdgcn_mfma_i32_16x16x64_i8(
                        a[mf][ks], b[nf][ks], acc[mh * 4 + mf][nf], 0, 0, 0);
    };
    auto compute = [&](int bs) {
        rdB(bs);
        rdA(bs, 0);
        mm(0);
        rdA(bs, 64);
        mm(1);
    };

    stage(0, 0);
    __syncthreads();
#pragma unroll 1
    for (int t = 0; t < 16; t += 2) {
        stage(1, t + 1);
        compute(0);
        __syncthreads();
        if (t + 2 < 16) stage(0, t + 2);
        compute(1);
        __syncthreads();
    }

    u16* flat = (u16*)SHM;  // 131072 B = [256][256] u16
#pragma unroll
    for (int mf = 0; mf < 8; ++mf)
#pragma unroll
        for (int nf = 0; nf < 4; ++nf)
#pragma unroll
            for (int rg = 0; rg < 4; ++rg) {
                int row = wr * 128 + mf * 16 + (lane >> 4) * 4 + rg;
                int col = wc * 64 + nf * 16 + l15;
                flat[row * 256 + (col ^ ((row & 7) << 3))] = f2bf((float)acc[mf][nf][rg]);
            }
    __syncthreads();
    int row = tid >> 1;
    if (m0 + row < cnt) {
        float s = sx[pairTok[base + m0 + row]];
        int xr = (row & 7) << 3;
        int half = tid & 1;
        u16* dst = C + (long)(base + m0 + row) * I_ + n0 + half * 64;
#pragma unroll
        for (int jj = 0; jj < 8; ++jj) {
            u16x8 gv = *(const u16x8*)&flat[row * 256 + ((half * 64 + jj * 8) ^ xr)];
            u16x8 uv = *(const u16x8*)&flat[row * 256 + ((128 + half * 64 + jj * 8) ^ xr)];
            u16x8 r;
#pragma unroll
            for (int q = 0; q < 8; ++q) {
                float g = bf2f(gv[q]) * s, u = bf2f(uv[q]) * s;
                r[q] = f2bf(g / (1.0f + expf(-g)) * u);
            }
            *(u16x8*)(dst + jj * 8) = r;
        }
    }
}

// ---------------- GEMM2: bf16 256x256 2-phase ----------------
__global__ __launch_bounds__(512, 2) void k_g2(
    const u16* __restrict__ A,      // ab [NPAIR][I] bf16, list order
    const u16* __restrict__ B,      // wb2 [E][K][I] bf16 (alpha2 folded)
    const int* __restrict__ pairTok, const int* __restrict__ offsets,
    u16* __restrict__ C)            // yb [NPAIR][K] scattered by pair
{
    int bid = blockIdx.x;
    int e  = bid & 7;
    int r_ = bid >> 3;
    int mc = r_ >> 3;
    int nch = r_ & 7;
    int base = offsets[e];
    int cnt  = offsets[e + 1] - base;
    int m0 = mc * 256;
    if (m0 >= cnt) return;
    int n0 = nch * 256;

    __shared__ __attribute__((aligned(16))) char SHM[131072];
    u16* ldsA = (u16*)SHM;               // [2][256][64] u16 = 64 KB
    u16* ldsB = (u16*)(SHM + 65536);     // [2][256][64] u16 = 64 KB

    int tid = threadIdx.x;
    int lane = tid & 63;
    int wid = tid >> 6;
    int wr = wid >> 2, wc = wid & 3;
    int l15 = lane & 15;

    const u16* srcA[2][2];
    const u16* srcB[2][2];
#pragma unroll
    for (int h = 0; h < 2; ++h)
#pragma unroll
        for (int j = 0; j < 2; ++j) {
            int slot = j * 512 + tid;
            int row = slot >> 3, ch = slot & 7;
            int colsw = (ch ^ (row & 7)) * 8;
            int ra = m0 + h * 128 + row;
            if (ra >= cnt) ra = cnt - 1;
            srcA[h][j] = A + (long)(base + ra) * I_ + colsw;
            long brow = (long)e * K_ + n0 + h * 128 + row;
            srcB[h][j] = B + brow * (long)I_ + colsw;
        }
    int d0 = tid * 8, d1 = (512 + tid) * 8;

    auto stage = [&](int bs, int t) {
        int k0 = t * 64;
        u16* dA = ldsA + bs * 16384;
        u16* dB = ldsB + bs * 16384;
#pragma unroll
        for (int h = 0; h < 2; ++h) {
            gld16(srcA[h][0] + k0, dA + h * 8192 + d0);
            gld16(srcA[h][1] + k0, dA + h * 8192 + d1);
            gld16(srcB[h][0] + k0, dB + h * 8192 + d0);
            gld16(srcB[h][1] + k0, dB + h * 8192 + d1);
        }
    };

    int kc0 = ((((lane >> 4) & 3) * 8)) ^ ((lane & 7) * 8);
    int kc1 = (32 + (((lane >> 4) & 3) * 8)) ^ ((lane & 7) * 8);

    bf16x8 a[4][2], b[4][2];
    f32x4 acc[8][4];
#pragma unroll
    for (int mf = 0; mf < 8; ++mf)
#pragma unroll
        for (int nf = 0; nf < 4; ++nf)
            acc[mf][nf] = (f32x4){0.f, 0.f, 0.f, 0.f};

    auto rdA = [&](int bs, int h64) {
#pragma unroll
        for (int mf = 0; mf < 4; ++mf) {
            const u16* p = ldsA + bs * 16384 + (wr * 128 + h64 + mf * 16 + l15) * 64;
            a[mf][0] = __builtin_bit_cast(bf16x8, *(const u16x8*)(p + kc0));
            a[mf][1] = __builtin_bit_cast(bf16x8, *(const u16x8*)(p + kc1));
        }
    };
    auto rdB = [&](int bs) {
#pragma unroll
        for (int nf = 0; nf < 4; ++nf) {
            const u16* p = ldsB + bs * 16384 + (wc * 64 + nf * 16 + l15) * 64;
            b[nf][0] = __builtin_bit_cast(bf16x8, *(const u16x8*)(p + kc0));
            b[nf][1] = __builtin_bit_cast(bf16x8, *(const u16x8*)(p + kc1));
        }
    };
    auto mm = [&](int mh) {
#pragma unroll
        for (int ks = 0; ks < 2; ++ks)
#pragma unroll
            for (int mf = 0; mf < 4; ++mf)
#pragma unroll
                for (int nf = 0; nf < 4; ++nf)
                    acc[mh * 4 + mf][nf] = __builtin_amdgcn_mfma_f32_16x16x32_bf16(
                        a[mf][ks], b[nf][ks], acc[mh * 4 + mf][nf], 0, 0, 0);
    };
    auto compute = [&](int bs) {
        rdB(bs);
        rdA(bs, 0);
        mm(0);
        rdA(bs, 64);
        mm(1);
    };

    // NT = 12 (K-dim = I_ = 768, BK = 64)
    stage(0, 0);
    __syncthreads();
#pragma unroll 1
    for (int t = 0; t < 12; t += 2) {
        stage(1, t + 1);
        compute(0);
        __syncthreads();
        if (t + 2 < 12) stage(0, t + 2);
        compute(1);
        __syncthreads();
    }

    u16* flat = (u16*)SHM;  // 131072 B = [256][256] u16
#pragma unroll
    for (int mf = 0; mf < 8; ++mf)
#pragma unroll
        for (int nf = 0; nf < 4; ++nf)
#pragma unroll
            for (int rg = 0; rg < 4; ++rg) {
                int row = wr * 128 + mf * 16 + (lane >> 4) * 4 + rg;
                int col = wc * 64 + nf * 16 + l15;
                flat[row * 256 + (col ^ ((row & 7) << 3))] = f2bf(acc[mf][nf][rg]);
            }
    __syncthreads();
    int row = tid >> 1;
    if (m0 + row < cnt) {
        int xr = (row & 7) << 3;
        int half = tid & 1;
        int pt = pairTok[base + m0 + row];
        u16* dst = C + (long)pt * K_ + n0 + half * 128;
#pragma unroll
        for (int jj = 0; jj < 16; ++jj) {
            *(u16x8*)(dst + jj * 8) =
                *(const u16x8*)&flat[row * 256 + ((half * 128 + jj * 8) ^ xr)];
        }
    }
}

// ---------------- combine ----------------
__global__ void k_combine(const u16* __restrict__ yb, const float* __restrict__ tw,
                          float* __restrict__ out) {
    long idx = ((long)blockIdx.x * 256 + threadIdx.x) * 8;
    int t = (int)(idx >> 11);
    float w0 = tw[t * 2 + 0];
    float w1 = tw[t * 2 + 1];
    u16x8 y0 = *(const u16x8*)(yb + (long)(2 * t) * K_ + (idx & (K_ - 1)));
    u16x8 y1 = *(const u16x8*)(yb + (long)(2 * t + 1) * K_ + (idx & (K_ - 1)));
    float4v o0, o1;
#pragma unroll
    for (int j = 0; j < 4; ++j) o0[j] = w0 * bf2f(y0[j]) + w1 * bf2f(y1[j]);
#pragma unroll
    for (int j = 0; j < 4; ++j) o1[j] = w0 * bf2f(y0[4 + j]) + w1 * bf2f(y1[4 + j]);
    *(float4v*)(out + idx) = o0;
    *(float4v*)(out + idx + 4) = o1;
}

// ---------------- launch ----------------
extern "C" void kernel_launch(void* const* d_in, const int* in_sizes, int n_in,
                              void* d_out, int out_size, void* d_ws, size_t ws_size,
                              hipStream_t stream) {
    const float* x       = (const float*)d_in[0];
    const float* logits  = (const float*)d_in[1];
    const int*   w13q    = (const int*)d_in[2];
    const int*   w2q     = (const int*)d_in[3];
    const float* alpha13 = (const float*)d_in[4];
    const float* alpha2  = (const float*)d_in[5];
    float* out = (float*)d_out;

    char* ws = (char*)d_ws;
    i8*  wc13 = (i8*)(ws);                          // 25165824 B (codes i8)
    u16* wb2  = (u16*)(ws + 50331648);              // 25165824 B (bf16, alpha2 folded)
    i8*  xq   = (i8*)(ws + 75497472);               // 16777216 B (pair-id order)
    u16* ab   = (u16*)(ws + 92274688);              // 12582912 B (silu*u bf16, list order)
    u16* yb   = (u16*)(ws + 104857600);             // 33554432 B
    int* pairTok = (int*)(ws + 138412032);          // 8192 ints
    int* tid2    = pairTok + NPAIR;                 // 8192 ints
    float* tw    = (float*)(tid2 + NPAIR);          // 8192 floats
    int* counts  = (int*)(tw + NPAIR);              // 8 (unused)
    int* offsets = counts + 8;                      // 9
    int* cursors = offsets + 9;                     // 8
    float* sx    = (float*)(cursors + 8);           // 8192 floats (pair-id order)

    // fused: both weight conversions + self-routed per-pair quantization
    k_fusedA<<<QX_BASE + NPAIR, 256, 0, stream>>>(
        w13q, w2q, alpha2, logits, x, alpha13, wc13, wb2, xq, sx, tid2, tw, cursors);

    // histogram + offsets + per-expert token lists (single dispatch)
    k_lists2<<<T_ / 256, 256, 0, stream>>>(tid2, offsets, cursors, pairTok);

    // GEMM1 i8 (M x [128g|128u] x 2048) + fused silu*u -> ab
    k_g1i8<<<8 * (T_ / 256) * 6, 512, 0, stream>>>(xq, wc13, pairTok, offsets, sx, ab);

    // GEMM2 bf16 (M x 2048 x 768) -> yb scattered by pair
    k_g2<<<8 * (T_ / 256) * (K_ / 256), 512, 0, stream>>>(ab, wb2, pairTok, offsets, yb);

    // combine
    k_combine<<<((long)T_ * K_) / 8 / 256, 256, 0, stream>>>(yb, tw, out);
}